// Round 2
// baseline (306.428 us; speedup 1.0000x reference)
//
#include <hip/hip_runtime.h>

typedef unsigned long long u64;
typedef float f2 __attribute__((ext_vector_type(2)));
typedef float f4 __attribute__((ext_vector_type(4)));

// Problem constants (match reference setup_inputs)
#define NSETS 8
#define NPTS  4096
#define DF    16
#define KNN   16
#define QPB   64                  // queries per block (one per lane)
#define NCH   8                   // waves per block
#define BLK   (QPB * NCH)         // 512 threads
#define TILE  512                 // candidates staged into LDS per tile
#define NTILE (NPTS / TILE)       // 8
#define SLICE (TILE / NCH)        // 64 candidates per wave per tile
#define PAIRS (SLICE / 2)         // 32 candidate pairs per wave per tile
#define NEDGE (NSETS * NPTS * KNN)

// Round-9: r8 showed batch-flush neutral (flushes are ~10 VALU/cand amortized,
// not 60) but MPAD killed the 2M bank conflicts. Still VALU-bound (80% busy,
// HBM 0.9%): the scan body itself dominates — 16 serially-dependent v_fma_f32
// per candidate + insert path. Fix: packed FP32 (v_pk_fma_f32, gfx90a+ VOP3P).
// Process candidate PAIRS with float2 ext-vector math: 16 pk_fma + 2 pk_add
// per pair replaces 32 fma + 4 add, with each candidate's fma tree (d0..d15
// sequential, then (q2+nc)+dot) BIT-IDENTICAL to r8 -> same selection, same
// output bytes. LDS layout pair-interleaved: pf[j][cp]={A.d2j,B.d2j,A.d2j+1,
// B.d2j+1}. Insert path gated behind __any to skip pack/store when no lane
// inserts. Flush/merge/tau machinery unchanged from r8.
#define RES      8                // reservoir slots/lane (max cnt = 4+GRP = 8)
#define FLUSH_AT 5                // flush when any lane cnt >= this
#define GRPP     2                // pairs between flush checks (=4 candidates)

#define FEAT_B   (TILE * DF * 4)            // 32768 B: pf[8][TILE/2] float4
#define NRM_B    (TILE * 4)                 // 2048 B:  nrm2[TILE/2] float2
#define RESV_OFF (FEAT_B + NRM_B)           // 34816
#define SMEM_B   (RESV_OFF + RES * BLK * 8) // 67584 B -> 2 blocks/CU
#define MPAD     17                         // merge-overlay stride (17 coprime 32)

// positive/negative-safe orderable-uint mapping for f32 (handles the ~±0
// diagonal self-distance)
__device__ __forceinline__ unsigned flip_f(float d) {
    unsigned b = __float_as_uint(d);
    return (b & 0x80000000u) ? ~b : (b | 0x80000000u);
}
__device__ __forceinline__ float unflip_f(unsigned u) {
    unsigned b = (u & 0x80000000u) ? (u ^ 0x80000000u) : ~u;
    return __uint_as_float(b);
}

__device__ __forceinline__ f2 sp2(float v) { f2 r = {v, v}; return r; }

__device__ __forceinline__ f2 fma2(f2 a, f2 b, f2 c) {
#if __has_builtin(__builtin_elementwise_fma)
    return __builtin_elementwise_fma(a, b, c);
#else
    f2 r; r.x = fmaf(a.x, b.x, c.x); r.y = fmaf(a.y, b.y, c.y); return r;
#endif
}

// compare-exchange: ascending (min at i), u64 key carries (dist, idx)
#define CEB(i, j) { u64 _a = B[i], _b = B[j]; bool _c = _b < _a; \
                    B[i] = _c ? _b : _a; B[j] = _c ? _a : _b; }
#define CEL(i, j) { u64 _a = Lk[i], _b = Lk[j]; bool _c = _b < _a; \
                    Lk[i] = _c ? _b : _a; Lk[j] = _c ? _a : _b; }

__global__ __launch_bounds__(BLK) void knn_kernel(const float* __restrict__ x,
                                                  float* __restrict__ out) {
    __shared__ float tau_sh[QPB];                 // shared per-query tau
    __shared__ __align__(16) char smem[SMEM_B];
    f4*  pf   = (f4*)smem;                        // pf[j*256 + cp], j=0..7
    f2*  nrm2 = (f2*)(smem + FEAT_B);             // candidate norm pairs
    u64* resv = (u64*)(smem + RESV_OFF);          // resv[slot*BLK + t]
    float*          lds_d = (float*)smem;                     // overlay (post-scan)
    unsigned short* lds_i = (unsigned short*)(smem + BLK * MPAD * 4);

    const int t    = threadIdx.x;
    const int lane = t & 63;
    const int wv   = t >> 6;                    // slice index 0..7
    const int set  = blockIdx.x >> 6;           // 64 blocks per set
    const int q0   = (blockIdx.x & 63) * QPB;
    const int q    = q0 + lane;                 // this lane's query point

    const float* xs = x + (size_t)set * NPTS * DF;

    if (t < QPB) tau_sh[t] = 3.0e38f;

    // Query features; q2 via the SAME pairwise tree as candidate norms (bit-
    // identical to prior rounds). qn = -2*q: exact pow2 scaling commutes with
    // fma rounding -> dist bit-identical to r8.
    float qn[DF];
    float q2;
    {
        const float4* qp = (const float4*)(xs + (size_t)q * DF);
        float4 a = qp[0], b = qp[1], g = qp[2], d = qp[3];
        float r0 = __fadd_rn(__fmul_rn(a.x, a.x), __fmul_rn(g.x, g.x));
        float r1 = __fadd_rn(__fmul_rn(a.y, a.y), __fmul_rn(g.y, g.y));
        float r2 = __fadd_rn(__fmul_rn(a.z, a.z), __fmul_rn(g.z, g.z));
        float r3 = __fadd_rn(__fmul_rn(a.w, a.w), __fmul_rn(g.w, g.w));
        float r4 = __fadd_rn(__fmul_rn(b.x, b.x), __fmul_rn(d.x, d.x));
        float r5 = __fadd_rn(__fmul_rn(b.y, b.y), __fmul_rn(d.y, d.y));
        float r6 = __fadd_rn(__fmul_rn(b.z, b.z), __fmul_rn(d.z, d.z));
        float r7 = __fadd_rn(__fmul_rn(b.w, b.w), __fmul_rn(d.w, d.w));
        q2 = __fadd_rn(__fadd_rn(__fadd_rn(r0, r1), __fadd_rn(r2, r3)),
                       __fadd_rn(__fadd_rn(r4, r5), __fadd_rn(r6, r7)));
        qn[0]=a.x; qn[1]=a.y; qn[2]=a.z; qn[3]=a.w;
        qn[4]=b.x; qn[5]=b.y; qn[6]=b.z; qn[7]=b.w;
        qn[8]=g.x; qn[9]=g.y; qn[10]=g.z; qn[11]=g.w;
        qn[12]=d.x; qn[13]=d.y; qn[14]=d.z; qn[15]=d.w;
#pragma unroll
        for (int d2 = 0; d2 < DF; ++d2) qn[d2] = -2.0f * qn[d2];
    }
    const f2 q22 = sp2(q2);

    // Sorted (ascending) top-16 as packed u64 keys. Sentinel unflips to 3e38.
    const u64 SENT = ((u64)flip_f(3.0e38f) << 32) | 0xFFFFFFFFull;
    u64   Lk[KNN];
#pragma unroll
    for (int j = 0; j < KNN; ++j) Lk[j] = SENT;
    float tau_reg = 3.0e38f;     // == unflip(Lk[15]) at all flush boundaries
    int   cnt = 0;

    // Divergence-free batch drain: sort the 8-slot reservoir (sentinel-padded
    // per lane), min-pair into the tail of Lk, bitonic-merge-16 back to
    // sorted. Key order is exact (dist, idx) lexicographic.
    auto flush = [&]() {
        u64 B[RES];
#pragma unroll
        for (int e = 0; e < RES; ++e) {
            u64 v = resv[e * BLK + t];
            B[e] = (e < cnt) ? v : SENT;
        }
        // Batcher odd-even mergesort, 8 keys, 19 CEs
        CEB(0,1) CEB(2,3) CEB(4,5) CEB(6,7)
        CEB(0,2) CEB(1,3) CEB(4,6) CEB(5,7)
        CEB(1,2) CEB(5,6)
        CEB(0,4) CEB(1,5) CEB(2,6) CEB(3,7)
        CEB(2,4) CEB(3,5)
        CEB(1,2) CEB(3,4) CEB(5,6)
        // keep-16: L[15-i] = min(L[15-i], B[i]) -> L becomes bitonic
#pragma unroll
        for (int i = 0; i < RES; ++i) {
            u64 a = Lk[KNN - 1 - i], b = B[i];
            Lk[KNN - 1 - i] = (b < a) ? b : a;
        }
        // bitonic merge 16 -> ascending
        CEL(0,8)  CEL(1,9)  CEL(2,10) CEL(3,11)
        CEL(4,12) CEL(5,13) CEL(6,14) CEL(7,15)
        CEL(0,4)  CEL(1,5)  CEL(2,6)  CEL(3,7)
        CEL(8,12) CEL(9,13) CEL(10,14) CEL(11,15)
        CEL(0,2)  CEL(1,3)  CEL(4,6)  CEL(5,7)
        CEL(8,10) CEL(9,11) CEL(12,14) CEL(13,15)
        CEL(0,1)  CEL(2,3)  CEL(4,5)  CEL(6,7)
        CEL(8,9)  CEL(10,11) CEL(12,13) CEL(14,15)
        cnt = 0;
        const float kth = unflip_f((unsigned)(Lk[KNN - 1] >> 32));
        tau_reg = kth;
        volatile float* ts = (volatile float*)tau_sh;   // benign-race cons. min
        float cur = ts[lane];
        ts[lane] = fminf(cur, kth);
    };

    for (int tile = 0; tile < NTILE; ++tile) {
        __syncthreads();   // previous tile fully consumed (also covers tau init)
        {
            // Thread t stages candidate tile*TILE+t into the pair-interleaved
            // layout: pf[j][cp] = {even.d2j, odd.d2j, even.d2j+1, odd.d2j+1}.
            // Norm via the exact Phase-A tree (unchanged values).
            const int c = tile * TILE + t;
            const float4* p = (const float4*)(xs + (size_t)c * DF);
            float4 a = p[0], b = p[1], g = p[2], d = p[3];
            float r0 = __fadd_rn(__fmul_rn(a.x, a.x), __fmul_rn(g.x, g.x));
            float r1 = __fadd_rn(__fmul_rn(a.y, a.y), __fmul_rn(g.y, g.y));
            float r2 = __fadd_rn(__fmul_rn(a.z, a.z), __fmul_rn(g.z, g.z));
            float r3 = __fadd_rn(__fmul_rn(a.w, a.w), __fmul_rn(g.w, g.w));
            float r4 = __fadd_rn(__fmul_rn(b.x, b.x), __fmul_rn(d.x, d.x));
            float r5 = __fadd_rn(__fmul_rn(b.y, b.y), __fmul_rn(d.y, d.y));
            float r6 = __fadd_rn(__fmul_rn(b.z, b.z), __fmul_rn(d.z, d.z));
            float r7 = __fadd_rn(__fmul_rn(b.w, b.w), __fmul_rn(d.w, d.w));
            const int cp  = t >> 1;
            const int sub = t & 1;
            float* w0 = (float*)&pf[0 * 256 + cp];
            float* w1 = (float*)&pf[1 * 256 + cp];
            float* w2 = (float*)&pf[2 * 256 + cp];
            float* w3 = (float*)&pf[3 * 256 + cp];
            float* w4 = (float*)&pf[4 * 256 + cp];
            float* w5 = (float*)&pf[5 * 256 + cp];
            float* w6 = (float*)&pf[6 * 256 + cp];
            float* w7 = (float*)&pf[7 * 256 + cp];
            w0[sub] = a.x; w0[sub + 2] = a.y;
            w1[sub] = a.z; w1[sub + 2] = a.w;
            w2[sub] = b.x; w2[sub + 2] = b.y;
            w3[sub] = b.z; w3[sub + 2] = b.w;
            w4[sub] = g.x; w4[sub + 2] = g.y;
            w5[sub] = g.z; w5[sub + 2] = g.w;
            w6[sub] = d.x; w6[sub + 2] = d.y;
            w7[sub] = d.z; w7[sub + 2] = d.w;
            ((float*)nrm2)[t] = __fadd_rn(
                __fadd_rn(__fadd_rn(r0, r1), __fadd_rn(r2, r3)),
                __fadd_rn(__fadd_rn(r4, r5), __fadd_rn(r6, r7)));
        }
        __syncthreads();

        const int pbase = wv * PAIRS;            // pair base in tile
        const int gbase = tile * TILE;           // global candidate base of tile

        for (int g = 0; g < PAIRS; g += GRPP) {
            const float tsh = ((volatile float*)tau_sh)[lane];
            const float tau = fminf(tsh, tau_reg);
#pragma unroll
            for (int u = 0; u < GRPP; ++u) {
                const int lp = pbase + g + u;    // wave-uniform pair index
                const f4* pp = pf + lp;
                f4 c0 = pp[0 * 256];
                f4 c1 = pp[1 * 256];
                f4 c2 = pp[2 * 256];
                f4 c3 = pp[3 * 256];
                f4 c4 = pp[4 * 256];
                f4 c5 = pp[5 * 256];
                f4 c6 = pp[6 * 256];
                f4 c7 = pp[7 * 256];
                const f2 nn = nrm2[lp];
                f2 acc = {0.f, 0.f};
                acc = fma2(sp2(qn[0]),  c0.lo, acc);
                acc = fma2(sp2(qn[1]),  c0.hi, acc);
                acc = fma2(sp2(qn[2]),  c1.lo, acc);
                acc = fma2(sp2(qn[3]),  c1.hi, acc);
                acc = fma2(sp2(qn[4]),  c2.lo, acc);
                acc = fma2(sp2(qn[5]),  c2.hi, acc);
                acc = fma2(sp2(qn[6]),  c3.lo, acc);
                acc = fma2(sp2(qn[7]),  c3.hi, acc);
                acc = fma2(sp2(qn[8]),  c4.lo, acc);
                acc = fma2(sp2(qn[9]),  c4.hi, acc);
                acc = fma2(sp2(qn[10]), c5.lo, acc);
                acc = fma2(sp2(qn[11]), c5.hi, acc);
                acc = fma2(sp2(qn[12]), c6.lo, acc);
                acc = fma2(sp2(qn[13]), c6.hi, acc);
                acc = fma2(sp2(qn[14]), c7.lo, acc);
                acc = fma2(sp2(qn[15]), c7.hi, acc);
                // dist = (q2 + nc) + dot, elementwise IEEE adds -> bit-
                // identical to r8's __fadd_rn tree per candidate.
                const f2 d2 = (q22 + nn) + acc;
                const bool iA = d2.x <= tau;     // non-strict: keep boundary ties
                const bool iB = d2.y <= tau;
                if (__any(iA | iB)) {
                    const int gA = gbase + (lp << 1);
                    if (iA) {
                        resv[cnt * BLK + t] =
                            ((u64)flip_f(d2.x) << 32) | (unsigned)gA;
                        ++cnt;
                    }
                    if (iB) {
                        resv[cnt * BLK + t] =
                            ((u64)flip_f(d2.y) << 32) | (unsigned)(gA + 1);
                        ++cnt;
                    }
                }
            }
            if (__any(cnt >= FLUSH_AT)) flush();
        }
    }
    flush();                                      // final drain

    // ---- Merge the 8 per-slice lists and emit ------------------------------
    __syncthreads();   // overlay aliases tile + other threads' reservoir slots
#pragma unroll
    for (int j = 0; j < KNN; ++j) {
        lds_d[t * MPAD + j] = unflip_f((unsigned)(Lk[j] >> 32));
        lds_i[t * MPAD + j] = (unsigned short)(Lk[j] & 0xFFFFu);
    }
    __syncthreads();

    if (t < QPB) {
        const int l = t;
        float h[NCH];
        int   hi[NCH];
        int   p[NCH];
#pragma unroll
        for (int w2 = 0; w2 < NCH; ++w2) {
            p[w2]  = 0;
            h[w2]  = lds_d[(w2 * QPB + l) * MPAD];
            hi[w2] = (int)lds_i[(w2 * QPB + l) * MPAD];
        }

        const int    gq = set * NPTS + q0 + l;
        const size_t eb = (size_t)gq * KNN;
        float* osrc = out;
        float* odst = out + (size_t)NEDGE;
        float* odis = out + 2 * (size_t)NEDGE;
        const float srcf = (float)gq;

        for (int e = 0; e < KNN; ++e) {
            // (dist, idx) lexicographic min across the 8 heads — exact stable
            // top-k order (slices are strided, so idx must break ties).
            float best = h[0];
            int   bi   = hi[0];
            int   bw   = 0;
#pragma unroll
            for (int w2 = 1; w2 < NCH; ++w2) {
                const bool better = (h[w2] < best) ||
                                    (h[w2] == best && hi[w2] < bi);
                if (better) { best = h[w2]; bi = hi[w2]; bw = w2; }
            }

#pragma unroll
            for (int w2 = 0; w2 < NCH; ++w2) {
                if (bw == w2) {
                    ++p[w2];
                    if (p[w2] < KNN) {
                        h[w2]  = lds_d[(w2 * QPB + l) * MPAD + p[w2]];
                        hi[w2] = (int)lds_i[(w2 * QPB + l) * MPAD + p[w2]];
                    } else {
                        h[w2]  = 3.0e38f;
                        hi[w2] = 0x7FFFFFFF;
                    }
                }
            }

            osrc[eb + e] = srcf;
            odst[eb + e] = (float)(set * NPTS + bi);
            odis[eb + e] = best;
        }
    }
}

// ---------------------------------------------------------------------------
extern "C" void kernel_launch(void* const* d_in, const int* in_sizes, int n_in,
                              void* d_out, int out_size, void* d_ws, size_t ws_size,
                              hipStream_t stream) {
    (void)in_sizes; (void)n_in; (void)out_size; (void)d_ws; (void)ws_size;
    const float* x = (const float*)d_in[0];  // (8, 4096, 16) f32
    float* out = (float*)d_out;              // [src|dst|dist] f32

    knn_kernel<<<NSETS * (NPTS / QPB), BLK, 0, stream>>>(x, out);
}

// Round 3
// 212.543 us; speedup vs baseline: 1.4417x; 1.4417x over previous
//
#include <hip/hip_runtime.h>

typedef unsigned long long u64;

// Problem constants (match reference setup_inputs)
#define NSETS 8
#define NPTS  4096
#define DF    16
#define KNN   16
#define QPB   64                  // queries per block (one per lane)
#define NCH   8                   // waves per block
#define BLK   (QPB * NCH)         // 512 threads
#define TILE  512                 // candidates staged into LDS per tile
#define NTILE (NPTS / TILE)       // 8
#define SLICE (TILE / NCH)        // 64 candidates per wave per tile
#define NEDGE (NSETS * NPTS * KNN)

// Round-10: r9 post-mortem — pk_fma cut VALU work 20% but halved chain-ILP
// and went latency-bound (VALUBusy 80->47, dur +38%). Reverted. r8 issue
// accounting: ~48k instr/lane, dist=12k -> ~36k is selection, dominated by
// the ~350-VALU wave-wide drain network whose frequency is set by the
// hottest lane hitting FLUSH_AT=5 (reservoir capacity-starved at RES=8).
// r10: enlarge reservoir to an append-list (RES=10, FLUSH_AT=7) -> ~40%
// fewer drains for +8KB LDS (75.8KB/block, still 2 blocks/CU). Drain does
// the r8 sort8+keep16+merge16 on slots 0..7, plus a cheap second round
// (sort2+minpair+merge16) only when __any(cnt>8). Distance tree, (dist,idx)
// comparator, tau protocol, merge phase untouched -> bit-identical output.
#define RES      10               // append-list slots/lane
#define FLUSH_AT 7                // drain when any lane cnt >= this (post-group)
#define GRP      4                // candidates between drain checks

#define FEAT_B   (TILE * DF * 4)            // 32768 B: feat4[4][TILE] transposed
#define NRM_B    (TILE * 4)                 // 2048 B:  nrm_t[TILE]
#define RESV_OFF (FEAT_B + NRM_B)           // 34816
#define SMEM_B   (RESV_OFF + RES * BLK * 8) // 75776 B -> 2 blocks/CU (151.6KB)
#define MPAD     17                         // merge-overlay stride (17 coprime 32)

// positive/negative-safe orderable-uint mapping for f32 (handles the ~±0
// diagonal self-distance)
__device__ __forceinline__ unsigned flip_f(float d) {
    unsigned b = __float_as_uint(d);
    return (b & 0x80000000u) ? ~b : (b | 0x80000000u);
}
__device__ __forceinline__ float unflip_f(unsigned u) {
    unsigned b = (u & 0x80000000u) ? (u ^ 0x80000000u) : ~u;
    return __uint_as_float(b);
}

// compare-exchange: ascending (min at i), u64 key carries (dist, idx)
#define CEB(i, j) { u64 _a = B[i], _b = B[j]; bool _c = _b < _a; \
                    B[i] = _c ? _b : _a; B[j] = _c ? _a : _b; }
#define CEL(i, j) { u64 _a = Lk[i], _b = Lk[j]; bool _c = _b < _a; \
                    Lk[i] = _c ? _b : _a; Lk[j] = _c ? _a : _b; }
// bitonic merge 16 -> ascending (Lk[0..7] asc, Lk[8..15] from min-pair => bitonic)
#define MERGE16() \
    CEL(0,8)  CEL(1,9)  CEL(2,10) CEL(3,11)  \
    CEL(4,12) CEL(5,13) CEL(6,14) CEL(7,15)  \
    CEL(0,4)  CEL(1,5)  CEL(2,6)  CEL(3,7)   \
    CEL(8,12) CEL(9,13) CEL(10,14) CEL(11,15) \
    CEL(0,2)  CEL(1,3)  CEL(4,6)  CEL(5,7)   \
    CEL(8,10) CEL(9,11) CEL(12,14) CEL(13,15) \
    CEL(0,1)  CEL(2,3)  CEL(4,5)  CEL(6,7)   \
    CEL(8,9)  CEL(10,11) CEL(12,13) CEL(14,15)

__global__ __launch_bounds__(BLK) void knn_kernel(const float* __restrict__ x,
                                                  float* __restrict__ out) {
    __shared__ float tau_sh[QPB];                 // shared per-query tau
    __shared__ __align__(16) char smem[SMEM_B];
    float4* feat4 = (float4*)smem;                // feat4[r*TILE + c], r=0..3
    float*  nrm_t = (float*)(smem + FEAT_B);      // candidate norms
    u64*    resv  = (u64*)(smem + RESV_OFF);      // resv[slot*BLK + t], u64 keys
    float*          lds_d = (float*)smem;                     // overlay (post-scan)
    unsigned short* lds_i = (unsigned short*)(smem + BLK * MPAD * 4);

    const int t    = threadIdx.x;
    const int lane = t & 63;
    const int wv   = t >> 6;                    // slice index 0..7
    const int set  = blockIdx.x >> 6;           // 64 blocks per set
    const int q0   = (blockIdx.x & 63) * QPB;
    const int q    = q0 + lane;                 // this lane's query point

    const float* xs = x + (size_t)set * NPTS * DF;

    if (t < QPB) tau_sh[t] = 3.0e38f;

    // Query features; q2 via the SAME pairwise tree as candidate norms (bit-
    // identical to prior rounds). qn = -2*q: exact pow2 scaling commutes with
    // fma rounding -> dist bit-identical to r8.
    float qn[DF];
    float q2;
    {
        const float4* qp = (const float4*)(xs + (size_t)q * DF);
        float4 a = qp[0], b = qp[1], g = qp[2], d = qp[3];
        float r0 = __fadd_rn(__fmul_rn(a.x, a.x), __fmul_rn(g.x, g.x));
        float r1 = __fadd_rn(__fmul_rn(a.y, a.y), __fmul_rn(g.y, g.y));
        float r2 = __fadd_rn(__fmul_rn(a.z, a.z), __fmul_rn(g.z, g.z));
        float r3 = __fadd_rn(__fmul_rn(a.w, a.w), __fmul_rn(g.w, g.w));
        float r4 = __fadd_rn(__fmul_rn(b.x, b.x), __fmul_rn(d.x, d.x));
        float r5 = __fadd_rn(__fmul_rn(b.y, b.y), __fmul_rn(d.y, d.y));
        float r6 = __fadd_rn(__fmul_rn(b.z, b.z), __fmul_rn(d.z, d.z));
        float r7 = __fadd_rn(__fmul_rn(b.w, b.w), __fmul_rn(d.w, d.w));
        q2 = __fadd_rn(__fadd_rn(__fadd_rn(r0, r1), __fadd_rn(r2, r3)),
                       __fadd_rn(__fadd_rn(r4, r5), __fadd_rn(r6, r7)));
        qn[0]=a.x; qn[1]=a.y; qn[2]=a.z; qn[3]=a.w;
        qn[4]=b.x; qn[5]=b.y; qn[6]=b.z; qn[7]=b.w;
        qn[8]=g.x; qn[9]=g.y; qn[10]=g.z; qn[11]=g.w;
        qn[12]=d.x; qn[13]=d.y; qn[14]=d.z; qn[15]=d.w;
#pragma unroll
        for (int d2 = 0; d2 < DF; ++d2) qn[d2] = -2.0f * qn[d2];
    }

    // Sorted (ascending) top-16 as packed u64 keys. Sentinel unflips to 3e38.
    const u64 SENT = ((u64)flip_f(3.0e38f) << 32) | 0xFFFFFFFFull;
    u64   Lk[KNN];
#pragma unroll
    for (int j = 0; j < KNN; ++j) Lk[j] = SENT;
    float tau_reg = 3.0e38f;     // == unflip(Lk[15]) at all drain boundaries
    int   cnt = 0;

    // Divergence-free batch drain: sort slots 0..7 (sentinel-padded per lane),
    // min-pair into the tail of Lk (keeps the 16 smallest, leaves Lk bitonic),
    // bitonic-merge-16 back to sorted. Second round (rare) covers slots 8..9.
    // Key order is exact (dist, idx) lexicographic == reference stable order.
    auto drain = [&]() {
        {
            u64 B[8];
#pragma unroll
            for (int e = 0; e < 8; ++e) {
                u64 v = resv[e * BLK + t];
                B[e] = (e < cnt) ? v : SENT;
            }
            // Batcher odd-even mergesort, 8 keys, 19 CEs
            CEB(0,1) CEB(2,3) CEB(4,5) CEB(6,7)
            CEB(0,2) CEB(1,3) CEB(4,6) CEB(5,7)
            CEB(1,2) CEB(5,6)
            CEB(0,4) CEB(1,5) CEB(2,6) CEB(3,7)
            CEB(2,4) CEB(3,5)
            CEB(1,2) CEB(3,4) CEB(5,6)
            // keep-16: L[15-i] = min(L[15-i], B[i]) -> L becomes bitonic
#pragma unroll
            for (int i = 0; i < 8; ++i) {
                u64 a = Lk[KNN - 1 - i], b = B[i];
                Lk[KNN - 1 - i] = (b < a) ? b : a;
            }
            MERGE16()
        }
        if (__any(cnt > 8)) {        // rare second round: slots 8..9
            u64 c0 = resv[8 * BLK + t];
            u64 c1 = resv[9 * BLK + t];
            c0 = (8 < cnt) ? c0 : SENT;
            c1 = (9 < cnt) ? c1 : SENT;
            { u64 a = c0, b = c1; bool c = b < a; c0 = c ? b : a; c1 = c ? a : b; }
            { u64 a = Lk[15]; Lk[15] = (c0 < a) ? c0 : a; }
            { u64 a = Lk[14]; Lk[14] = (c1 < a) ? c1 : a; }
            MERGE16()
        }
        cnt = 0;
        const float kth = unflip_f((unsigned)(Lk[KNN - 1] >> 32));
        tau_reg = kth;
        volatile float* ts = (volatile float*)tau_sh;   // benign-race cons. min
        float cur = ts[lane];
        ts[lane] = fminf(cur, kth);
    };

    for (int tile = 0; tile < NTILE; ++tile) {
        __syncthreads();   // previous tile fully consumed (also covers tau init)
        {
            // Thread t stages candidate tile*TILE+t: features (transposed
            // float4 rows) + norm via the exact Phase-A tree, in registers.
            const int c = tile * TILE + t;
            const float4* p = (const float4*)(xs + (size_t)c * DF);
            float4 a = p[0], b = p[1], g = p[2], d = p[3];
            float r0 = __fadd_rn(__fmul_rn(a.x, a.x), __fmul_rn(g.x, g.x));
            float r1 = __fadd_rn(__fmul_rn(a.y, a.y), __fmul_rn(g.y, g.y));
            float r2 = __fadd_rn(__fmul_rn(a.z, a.z), __fmul_rn(g.z, g.z));
            float r3 = __fadd_rn(__fmul_rn(a.w, a.w), __fmul_rn(g.w, g.w));
            float r4 = __fadd_rn(__fmul_rn(b.x, b.x), __fmul_rn(d.x, d.x));
            float r5 = __fadd_rn(__fmul_rn(b.y, b.y), __fmul_rn(d.y, d.y));
            float r6 = __fadd_rn(__fmul_rn(b.z, b.z), __fmul_rn(d.z, d.z));
            float r7 = __fadd_rn(__fmul_rn(b.w, b.w), __fmul_rn(d.w, d.w));
            feat4[0 * TILE + t] = a;
            feat4[1 * TILE + t] = b;
            feat4[2 * TILE + t] = g;
            feat4[3 * TILE + t] = d;
            nrm_t[t] = __fadd_rn(
                __fadd_rn(__fadd_rn(r0, r1), __fadd_rn(r2, r3)),
                __fadd_rn(__fadd_rn(r4, r5), __fadd_rn(r6, r7)));
        }
        __syncthreads();

        const int lbase = wv * SLICE;            // local slice base in tile
        const int gbase = tile * TILE + lbase;   // global candidate id base

        for (int g = 0; g < SLICE; g += GRP) {
            const float tsh = ((volatile float*)tau_sh)[lane];
            const float tau = fminf(tsh, tau_reg);
#pragma unroll
            for (int u = 0; u < GRP; ++u) {
                const int lc = lbase + g + u;    // wave-uniform -> broadcast
                float4 f0 = feat4[0 * TILE + lc];
                float4 f1 = feat4[1 * TILE + lc];
                float4 f2 = feat4[2 * TILE + lc];
                float4 f3 = feat4[3 * TILE + lc];
                const float nc = nrm_t[lc];
                float dot = 0.f;
                dot = fmaf(qn[0],  f0.x, dot); dot = fmaf(qn[1],  f0.y, dot);
                dot = fmaf(qn[2],  f0.z, dot); dot = fmaf(qn[3],  f0.w, dot);
                dot = fmaf(qn[4],  f1.x, dot); dot = fmaf(qn[5],  f1.y, dot);
                dot = fmaf(qn[6],  f1.z, dot); dot = fmaf(qn[7],  f1.w, dot);
                dot = fmaf(qn[8],  f2.x, dot); dot = fmaf(qn[9],  f2.y, dot);
                dot = fmaf(qn[10], f2.z, dot); dot = fmaf(qn[11], f2.w, dot);
                dot = fmaf(qn[12], f3.x, dot); dot = fmaf(qn[13], f3.y, dot);
                dot = fmaf(qn[14], f3.z, dot); dot = fmaf(qn[15], f3.w, dot);
                const float dist = __fadd_rn(__fadd_rn(q2, nc), dot);
                if (dist <= tau) {               // non-strict: keep boundary ties
                    resv[cnt * BLK + t] =
                        ((u64)flip_f(dist) << 32) | (unsigned)(gbase + g + u);
                    ++cnt;
                }
            }
            if (__any(cnt >= FLUSH_AT)) drain();
        }
    }
    if (__any(cnt > 0)) drain();                  // final drain

    // ---- Merge the 8 per-slice lists and emit ------------------------------
    __syncthreads();   // overlay aliases tile + other threads' reservoir slots
#pragma unroll
    for (int j = 0; j < KNN; ++j) {
        lds_d[t * MPAD + j] = unflip_f((unsigned)(Lk[j] >> 32));
        lds_i[t * MPAD + j] = (unsigned short)(Lk[j] & 0xFFFFu);
    }
    __syncthreads();

    if (t < QPB) {
        const int l = t;
        float h[NCH];
        int   hi[NCH];
        int   p[NCH];
#pragma unroll
        for (int w2 = 0; w2 < NCH; ++w2) {
            p[w2]  = 0;
            h[w2]  = lds_d[(w2 * QPB + l) * MPAD];
            hi[w2] = (int)lds_i[(w2 * QPB + l) * MPAD];
        }

        const int    gq = set * NPTS + q0 + l;
        const size_t eb = (size_t)gq * KNN;
        float* osrc = out;
        float* odst = out + (size_t)NEDGE;
        float* odis = out + 2 * (size_t)NEDGE;
        const float srcf = (float)gq;

        for (int e = 0; e < KNN; ++e) {
            // (dist, idx) lexicographic min across the 8 heads — exact stable
            // top-k order (slices are strided, so idx must break ties).
            float best = h[0];
            int   bi   = hi[0];
            int   bw   = 0;
#pragma unroll
            for (int w2 = 1; w2 < NCH; ++w2) {
                const bool better = (h[w2] < best) ||
                                    (h[w2] == best && hi[w2] < bi);
                if (better) { best = h[w2]; bi = hi[w2]; bw = w2; }
            }

#pragma unroll
            for (int w2 = 0; w2 < NCH; ++w2) {
                if (bw == w2) {
                    ++p[w2];
                    if (p[w2] < KNN) {
                        h[w2]  = lds_d[(w2 * QPB + l) * MPAD + p[w2]];
                        hi[w2] = (int)lds_i[(w2 * QPB + l) * MPAD + p[w2]];
                    } else {
                        h[w2]  = 3.0e38f;
                        hi[w2] = 0x7FFFFFFF;
                    }
                }
            }

            osrc[eb + e] = srcf;
            odst[eb + e] = (float)(set * NPTS + bi);
            odis[eb + e] = best;
        }
    }
}

// ---------------------------------------------------------------------------
extern "C" void kernel_launch(void* const* d_in, const int* in_sizes, int n_in,
                              void* d_out, int out_size, void* d_ws, size_t ws_size,
                              hipStream_t stream) {
    (void)in_sizes; (void)n_in; (void)out_size; (void)d_ws; (void)ws_size;
    const float* x = (const float*)d_in[0];  // (8, 4096, 16) f32
    float* out = (float*)d_out;              // [src|dst|dist] f32

    knn_kernel<<<NSETS * (NPTS / QPB), BLK, 0, stream>>>(x, out);
}

// Round 4
// 199.786 us; speedup vs baseline: 1.5338x; 1.0639x over previous
//
#include <hip/hip_runtime.h>

typedef unsigned long long u64;

// Problem constants (match reference setup_inputs)
#define NSETS 8
#define NPTS  4096
#define DF    16
#define KNN   16
#define QPB   64                  // queries per block (one per lane)
#define NCH   8                   // waves per block
#define BLK   (QPB * NCH)         // 512 threads
#define TILE  512                 // candidates staged into LDS per tile
#define NTILE (NPTS / TILE)       // 8
#define SLICE (TILE / NCH)        // 64 candidates per wave per tile
#define NEDGE (NSETS * NPTS * KNN)

// Round-11: r10 confirmed drain-frequency theory (202->180) but capacity
// scaling is done. Remaining drain+insert cost is set by the INSERT RATE,
// which is set by tau looseness: tau = min_j(local 16th of wave j) sits at
// quantile 16/512 of each wave's stream vs global 16th at 16/4096 — ~5x
// insert-rate gap. Sound tighter bound: ANY 16 distinct elements have
// max >= global 16th, so max_j(wave j's 2nd smallest) >= global 16th, and
// the 2nd-of-512 quantile (2/512) == global-16th quantile (16/4096) ->
// near-tight. Exactness preserved: every global-top-16 member has dist <=
// global 16th <= tau at all times, passes the <= filter, and can't be
// evicted from its wave's local top-16 (17 keys <= 16th-smallest key is a
// contradiction). Implementation: tau2_sh[8][64]; each wave publishes
// unflip(Lk[1]) at drains (own slot, monotone, word-atomic), reads all 8,
// folds min(local16, max_j L2_j) into tau_reg/tau_sh. ~20 instr/drain;
// scan path unchanged; output bit-identical.
#define RES      10               // append-list slots/lane
#define FLUSH_AT 7                // drain when any lane cnt >= this (post-group)
#define GRP      4                // candidates between drain checks

#define FEAT_B   (TILE * DF * 4)            // 32768 B: feat4[4][TILE] transposed
#define NRM_B    (TILE * 4)                 // 2048 B:  nrm_t[TILE]
#define RESV_OFF (FEAT_B + NRM_B)           // 34816
#define SMEM_B   (RESV_OFF + RES * BLK * 8) // 75776 B (+tau arrays -> 2 blocks/CU)
#define MPAD     17                         // merge-overlay stride (17 coprime 32)

// positive/negative-safe orderable-uint mapping for f32 (handles the ~±0
// diagonal self-distance)
__device__ __forceinline__ unsigned flip_f(float d) {
    unsigned b = __float_as_uint(d);
    return (b & 0x80000000u) ? ~b : (b | 0x80000000u);
}
__device__ __forceinline__ float unflip_f(unsigned u) {
    unsigned b = (u & 0x80000000u) ? (u ^ 0x80000000u) : ~u;
    return __uint_as_float(b);
}

// compare-exchange: ascending (min at i), u64 key carries (dist, idx)
#define CEB(i, j) { u64 _a = B[i], _b = B[j]; bool _c = _b < _a; \
                    B[i] = _c ? _b : _a; B[j] = _c ? _a : _b; }
#define CEL(i, j) { u64 _a = Lk[i], _b = Lk[j]; bool _c = _b < _a; \
                    Lk[i] = _c ? _b : _a; Lk[j] = _c ? _a : _b; }
// bitonic merge 16 -> ascending (Lk[0..7] asc, Lk[8..15] from min-pair => bitonic)
#define MERGE16() \
    CEL(0,8)  CEL(1,9)  CEL(2,10) CEL(3,11)  \
    CEL(4,12) CEL(5,13) CEL(6,14) CEL(7,15)  \
    CEL(0,4)  CEL(1,5)  CEL(2,6)  CEL(3,7)   \
    CEL(8,12) CEL(9,13) CEL(10,14) CEL(11,15) \
    CEL(0,2)  CEL(1,3)  CEL(4,6)  CEL(5,7)   \
    CEL(8,10) CEL(9,11) CEL(12,14) CEL(13,15) \
    CEL(0,1)  CEL(2,3)  CEL(4,5)  CEL(6,7)   \
    CEL(8,9)  CEL(10,11) CEL(12,13) CEL(14,15)

__global__ __launch_bounds__(BLK) void knn_kernel(const float* __restrict__ x,
                                                  float* __restrict__ out) {
    __shared__ float tau_sh[QPB];                 // shared per-query tau (min fold)
    __shared__ float tau2_sh[NCH * QPB];          // per-wave 2nd-smallest per query
    __shared__ __align__(16) char smem[SMEM_B];
    float4* feat4 = (float4*)smem;                // feat4[r*TILE + c], r=0..3
    float*  nrm_t = (float*)(smem + FEAT_B);      // candidate norms
    u64*    resv  = (u64*)(smem + RESV_OFF);      // resv[slot*BLK + t], u64 keys
    float*          lds_d = (float*)smem;                     // overlay (post-scan)
    unsigned short* lds_i = (unsigned short*)(smem + BLK * MPAD * 4);

    const int t    = threadIdx.x;
    const int lane = t & 63;
    const int wv   = t >> 6;                    // slice index 0..7
    const int set  = blockIdx.x >> 6;           // 64 blocks per set
    const int q0   = (blockIdx.x & 63) * QPB;
    const int q    = q0 + lane;                 // this lane's query point

    const float* xs = x + (size_t)set * NPTS * DF;

    if (t < QPB) tau_sh[t] = 3.0e38f;
    tau2_sh[t] = 3.0e38f;                       // BLK == NCH*QPB, full coverage

    // Query features; q2 via the SAME pairwise tree as candidate norms (bit-
    // identical to prior rounds). qn = -2*q: exact pow2 scaling commutes with
    // fma rounding -> dist bit-identical to r10.
    float qn[DF];
    float q2;
    {
        const float4* qp = (const float4*)(xs + (size_t)q * DF);
        float4 a = qp[0], b = qp[1], g = qp[2], d = qp[3];
        float r0 = __fadd_rn(__fmul_rn(a.x, a.x), __fmul_rn(g.x, g.x));
        float r1 = __fadd_rn(__fmul_rn(a.y, a.y), __fmul_rn(g.y, g.y));
        float r2 = __fadd_rn(__fmul_rn(a.z, a.z), __fmul_rn(g.z, g.z));
        float r3 = __fadd_rn(__fmul_rn(a.w, a.w), __fmul_rn(g.w, g.w));
        float r4 = __fadd_rn(__fmul_rn(b.x, b.x), __fmul_rn(d.x, d.x));
        float r5 = __fadd_rn(__fmul_rn(b.y, b.y), __fmul_rn(d.y, d.y));
        float r6 = __fadd_rn(__fmul_rn(b.z, b.z), __fmul_rn(d.z, d.z));
        float r7 = __fadd_rn(__fmul_rn(b.w, b.w), __fmul_rn(d.w, d.w));
        q2 = __fadd_rn(__fadd_rn(__fadd_rn(r0, r1), __fadd_rn(r2, r3)),
                       __fadd_rn(__fadd_rn(r4, r5), __fadd_rn(r6, r7)));
        qn[0]=a.x; qn[1]=a.y; qn[2]=a.z; qn[3]=a.w;
        qn[4]=b.x; qn[5]=b.y; qn[6]=b.z; qn[7]=b.w;
        qn[8]=g.x; qn[9]=g.y; qn[10]=g.z; qn[11]=g.w;
        qn[12]=d.x; qn[13]=d.y; qn[14]=d.z; qn[15]=d.w;
#pragma unroll
        for (int d2 = 0; d2 < DF; ++d2) qn[d2] = -2.0f * qn[d2];
    }

    // Sorted (ascending) top-16 as packed u64 keys. Sentinel unflips to 3e38.
    const u64 SENT = ((u64)flip_f(3.0e38f) << 32) | 0xFFFFFFFFull;
    u64   Lk[KNN];
#pragma unroll
    for (int j = 0; j < KNN; ++j) Lk[j] = SENT;
    float tau_reg = 3.0e38f;
    int   cnt = 0;

    // Divergence-free batch drain: sort slots 0..7 (sentinel-padded per lane),
    // min-pair into the tail of Lk (keeps the 16 smallest, leaves Lk bitonic),
    // bitonic-merge-16 back to sorted. Second round (rare) covers slots 8..9.
    // Key order is exact (dist, idx) lexicographic == reference stable order.
    auto drain = [&]() {
        {
            u64 B[8];
#pragma unroll
            for (int e = 0; e < 8; ++e) {
                u64 v = resv[e * BLK + t];
                B[e] = (e < cnt) ? v : SENT;
            }
            // Batcher odd-even mergesort, 8 keys, 19 CEs
            CEB(0,1) CEB(2,3) CEB(4,5) CEB(6,7)
            CEB(0,2) CEB(1,3) CEB(4,6) CEB(5,7)
            CEB(1,2) CEB(5,6)
            CEB(0,4) CEB(1,5) CEB(2,6) CEB(3,7)
            CEB(2,4) CEB(3,5)
            CEB(1,2) CEB(3,4) CEB(5,6)
            // keep-16: L[15-i] = min(L[15-i], B[i]) -> L becomes bitonic
#pragma unroll
            for (int i = 0; i < 8; ++i) {
                u64 a = Lk[KNN - 1 - i], b = B[i];
                Lk[KNN - 1 - i] = (b < a) ? b : a;
            }
            MERGE16()
        }
        if (__any(cnt > 8)) {        // rare second round: slots 8..9
            u64 c0 = resv[8 * BLK + t];
            u64 c1 = resv[9 * BLK + t];
            c0 = (8 < cnt) ? c0 : SENT;
            c1 = (9 < cnt) ? c1 : SENT;
            { u64 a = c0, b = c1; bool c = b < a; c0 = c ? b : a; c1 = c ? a : b; }
            { u64 a = Lk[15]; Lk[15] = (c0 < a) ? c0 : a; }
            { u64 a = Lk[14]; Lk[14] = (c1 < a) ? c1 : a; }
            MERGE16()
        }
        cnt = 0;
        const float kth = unflip_f((unsigned)(Lk[KNN - 1] >> 32));
        // Global-tau tightening: publish my wave's 2nd smallest, take the max
        // over the 8 waves (>= global 16th, near-tight), fold with local 16th.
        volatile float* t2 = (volatile float*)tau2_sh;
        t2[wv * QPB + lane] = unflip_f((unsigned)(Lk[1] >> 32));
        float gmax = t2[0 * QPB + lane];
#pragma unroll
        for (int j = 1; j < NCH; ++j) gmax = fmaxf(gmax, t2[j * QPB + lane]);
        const float kth2 = fminf(kth, gmax);
        tau_reg = kth2;
        volatile float* ts = (volatile float*)tau_sh;   // benign-race cons. min
        float cur = ts[lane];
        ts[lane] = fminf(cur, kth2);
    };

    for (int tile = 0; tile < NTILE; ++tile) {
        __syncthreads();   // previous tile fully consumed (also covers tau init)
        {
            // Thread t stages candidate tile*TILE+t: features (transposed
            // float4 rows) + norm via the exact Phase-A tree, in registers.
            const int c = tile * TILE + t;
            const float4* p = (const float4*)(xs + (size_t)c * DF);
            float4 a = p[0], b = p[1], g = p[2], d = p[3];
            float r0 = __fadd_rn(__fmul_rn(a.x, a.x), __fmul_rn(g.x, g.x));
            float r1 = __fadd_rn(__fmul_rn(a.y, a.y), __fmul_rn(g.y, g.y));
            float r2 = __fadd_rn(__fmul_rn(a.z, a.z), __fmul_rn(g.z, g.z));
            float r3 = __fadd_rn(__fmul_rn(a.w, a.w), __fmul_rn(g.w, g.w));
            float r4 = __fadd_rn(__fmul_rn(b.x, b.x), __fmul_rn(d.x, d.x));
            float r5 = __fadd_rn(__fmul_rn(b.y, b.y), __fmul_rn(d.y, d.y));
            float r6 = __fadd_rn(__fmul_rn(b.z, b.z), __fmul_rn(d.z, d.z));
            float r7 = __fadd_rn(__fmul_rn(b.w, b.w), __fmul_rn(d.w, d.w));
            feat4[0 * TILE + t] = a;
            feat4[1 * TILE + t] = b;
            feat4[2 * TILE + t] = g;
            feat4[3 * TILE + t] = d;
            nrm_t[t] = __fadd_rn(
                __fadd_rn(__fadd_rn(r0, r1), __fadd_rn(r2, r3)),
                __fadd_rn(__fadd_rn(r4, r5), __fadd_rn(r6, r7)));
        }
        __syncthreads();

        const int lbase = wv * SLICE;            // local slice base in tile
        const int gbase = tile * TILE + lbase;   // global candidate id base

        for (int g = 0; g < SLICE; g += GRP) {
            const float tsh = ((volatile float*)tau_sh)[lane];
            const float tau = fminf(tsh, tau_reg);
#pragma unroll
            for (int u = 0; u < GRP; ++u) {
                const int lc = lbase + g + u;    // wave-uniform -> broadcast
                float4 f0 = feat4[0 * TILE + lc];
                float4 f1 = feat4[1 * TILE + lc];
                float4 f2 = feat4[2 * TILE + lc];
                float4 f3 = feat4[3 * TILE + lc];
                const float nc = nrm_t[lc];
                float dot = 0.f;
                dot = fmaf(qn[0],  f0.x, dot); dot = fmaf(qn[1],  f0.y, dot);
                dot = fmaf(qn[2],  f0.z, dot); dot = fmaf(qn[3],  f0.w, dot);
                dot = fmaf(qn[4],  f1.x, dot); dot = fmaf(qn[5],  f1.y, dot);
                dot = fmaf(qn[6],  f1.z, dot); dot = fmaf(qn[7],  f1.w, dot);
                dot = fmaf(qn[8],  f2.x, dot); dot = fmaf(qn[9],  f2.y, dot);
                dot = fmaf(qn[10], f2.z, dot); dot = fmaf(qn[11], f2.w, dot);
                dot = fmaf(qn[12], f3.x, dot); dot = fmaf(qn[13], f3.y, dot);
                dot = fmaf(qn[14], f3.z, dot); dot = fmaf(qn[15], f3.w, dot);
                const float dist = __fadd_rn(__fadd_rn(q2, nc), dot);
                if (dist <= tau) {               // non-strict: keep boundary ties
                    resv[cnt * BLK + t] =
                        ((u64)flip_f(dist) << 32) | (unsigned)(gbase + g + u);
                    ++cnt;
                }
            }
            if (__any(cnt >= FLUSH_AT)) drain();
        }
    }
    if (__any(cnt > 0)) drain();                  // final drain

    // ---- Merge the 8 per-slice lists and emit ------------------------------
    __syncthreads();   // overlay aliases tile + other threads' reservoir slots
#pragma unroll
    for (int j = 0; j < KNN; ++j) {
        lds_d[t * MPAD + j] = unflip_f((unsigned)(Lk[j] >> 32));
        lds_i[t * MPAD + j] = (unsigned short)(Lk[j] & 0xFFFFu);
    }
    __syncthreads();

    if (t < QPB) {
        const int l = t;
        float h[NCH];
        int   hi[NCH];
        int   p[NCH];
#pragma unroll
        for (int w2 = 0; w2 < NCH; ++w2) {
            p[w2]  = 0;
            h[w2]  = lds_d[(w2 * QPB + l) * MPAD];
            hi[w2] = (int)lds_i[(w2 * QPB + l) * MPAD];
        }

        const int    gq = set * NPTS + q0 + l;
        const size_t eb = (size_t)gq * KNN;
        float* osrc = out;
        float* odst = out + (size_t)NEDGE;
        float* odis = out + 2 * (size_t)NEDGE;
        const float srcf = (float)gq;

        for (int e = 0; e < KNN; ++e) {
            // (dist, idx) lexicographic min across the 8 heads — exact stable
            // top-k order (slices are strided, so idx must break ties).
            float best = h[0];
            int   bi   = hi[0];
            int   bw   = 0;
#pragma unroll
            for (int w2 = 1; w2 < NCH; ++w2) {
                const bool better = (h[w2] < best) ||
                                    (h[w2] == best && hi[w2] < bi);
                if (better) { best = h[w2]; bi = hi[w2]; bw = w2; }
            }

#pragma unroll
            for (int w2 = 0; w2 < NCH; ++w2) {
                if (bw == w2) {
                    ++p[w2];
                    if (p[w2] < KNN) {
                        h[w2]  = lds_d[(w2 * QPB + l) * MPAD + p[w2]];
                        hi[w2] = (int)lds_i[(w2 * QPB + l) * MPAD + p[w2]];
                    } else {
                        h[w2]  = 3.0e38f;
                        hi[w2] = 0x7FFFFFFF;
                    }
                }
            }

            osrc[eb + e] = srcf;
            odst[eb + e] = (float)(set * NPTS + bi);
            odis[eb + e] = best;
        }
    }
}

// ---------------------------------------------------------------------------
extern "C" void kernel_launch(void* const* d_in, const int* in_sizes, int n_in,
                              void* d_out, int out_size, void* d_ws, size_t ws_size,
                              hipStream_t stream) {
    (void)in_sizes; (void)n_in; (void)out_size; (void)d_ws; (void)ws_size;
    const float* x = (const float*)d_in[0];  // (8, 4096, 16) f32
    float* out = (float*)d_out;              // [src|dst|dist] f32

    knn_kernel<<<NSETS * (NPTS / QPB), BLK, 0, stream>>>(x, out);
}